// Round 1
// baseline (433.424 us; speedup 1.0000x reference)
//
#include <hip/hip_runtime.h>

#define NCOEF 66           // n = 70 - 3 - 1
#define H     (1.0f/69.0f) // uniform knot spacing

__device__ __forceinline__ float eval_spline(float xx, const float* __restrict__ c) {
    // interval: i = clamp(floor(x*69), 3, 65); trunc==floor except for negative
    // products, which clamp to 3 anyway.
    int i = (int)(xx * 69.0f);
    i = i < 3 ? 3 : (i > 65 ? 65 : i);

    float ti = (float)i * H;
    float u  = xx - ti;          // x - t[i]
    float u1 = u + H;            // x - t[i-1]
    float u2 = u + 2.0f * H;     // x - t[i-2]

    float d0 = c[i - 3];
    float d1 = c[i - 2];
    float d2 = c[i - 1];
    float d3 = c[i];

    float a;
    // r = 1: denom = 3h -> 1/denom = 23 (exact)
    a = u  * 23.0f; d3 = (1.0f - a) * d2 + a * d3;
    a = u1 * 23.0f; d2 = (1.0f - a) * d1 + a * d2;
    a = u2 * 23.0f; d1 = (1.0f - a) * d0 + a * d1;
    // r = 2: denom = 2h -> 34.5 (exact)
    a = u  * 34.5f; d3 = (1.0f - a) * d2 + a * d3;
    a = u1 * 34.5f; d2 = (1.0f - a) * d1 + a * d2;
    // r = 3: denom = h -> 69 (exact)
    a = u  * 69.0f; d3 = (1.0f - a) * d2 + a * d3;
    return d3;
}

__global__ __launch_bounds__(256) void spline_kernel(
    const float* __restrict__ x, const float* __restrict__ coef,
    float* __restrict__ out, int n)
{
    __shared__ float c[NCOEF];
    if (threadIdx.x < NCOEF) c[threadIdx.x] = coef[threadIdx.x];
    __syncthreads();

    const int n4     = n >> 2;
    const int stride = gridDim.x * blockDim.x;
    int idx = blockIdx.x * blockDim.x + threadIdx.x;

    for (; idx < n4; idx += stride) {
        float4 xv = reinterpret_cast<const float4*>(x)[idx];
        float4 ov;
        ov.x = eval_spline(xv.x, c);
        ov.y = eval_spline(xv.y, c);
        ov.z = eval_spline(xv.z, c);
        ov.w = eval_spline(xv.w, c);
        reinterpret_cast<float4*>(out)[idx] = ov;
    }

    // scalar tail (n not divisible by 4) — no-op for this problem's sizes
    int tail = (n4 << 2) + (blockIdx.x * blockDim.x + threadIdx.x);
    if (tail < n && (blockIdx.x * blockDim.x + threadIdx.x) < (n & 3)) {
        out[tail] = eval_spline(x[tail], c);
    }
}

extern "C" void kernel_launch(void* const* d_in, const int* in_sizes, int n_in,
                              void* d_out, int out_size, void* d_ws, size_t ws_size,
                              hipStream_t stream) {
    const float* x    = (const float*)d_in[0];
    const float* coef = (const float*)d_in[1];
    float* out        = (float*)d_out;
    int n = in_sizes[0];

    int n4 = n >> 2;
    int threads = 256;
    int blocks = 4096;                       // 16 blocks/CU, 16 float4/thread
    int max_blocks = (n4 + threads - 1) / threads;
    if (blocks > max_blocks) blocks = max_blocks;
    if (blocks < 1) blocks = 1;

    spline_kernel<<<blocks, threads, 0, stream>>>(x, coef, out, n);
}

// Round 2
// 431.841 us; speedup vs baseline: 1.0037x; 1.0037x over previous
//
#include <hip/hip_runtime.h>

#define NCOEF 66           // n = 70 - 3 - 1 usable coefficients

// Uniform knots t[k] = k/69. De Boor (p=3) on uniform knots == uniform cubic
// B-spline basis. Per interval i (clamped to [3,65]) with s = 69*x - i:
//   f = (1/6) * [ (1-s)^3 c[i-3] + (3s^3-6s^2+4) c[i-2]
//               + (-3s^3+3s^2+3s+1) c[i-1] + s^3 c[i] ]
// Power basis (exact polynomial identity, valid for extrapolation s<0 / s>1):
//   a0 = (c0 + 4c1 + c2)/6,  a1 = (c2 - c0)/2,
//   a2 = (c0 - 2c1 + c2)/2,  a3 = (c3 - c0 + 3(c1 - c2))/6
//   f  = ((a3*s + a2)*s + a1)*s + a0     (3 fma Horner)

__global__ __launch_bounds__(256) void spline_kernel(
    const float* __restrict__ x, const float* __restrict__ coef,
    float* __restrict__ out, int n)
{
    __shared__ float  sc[NCOEF];
    __shared__ float4 tab[NCOEF];   // 16B-aligned -> one ds_read_b128 per elem

    const int t = threadIdx.x;
    if (t < NCOEF) sc[t] = coef[t];
    __syncthreads();
    if (t >= 3 && t < NCOEF) {
        float c0 = sc[t - 3], c1 = sc[t - 2], c2 = sc[t - 1], c3 = sc[t];
        const float k6 = 1.0f / 6.0f;
        float a0 = (c0 + 4.0f * c1 + c2) * k6;
        float a1 = (c2 - c0) * 0.5f;
        float a2 = (c0 - 2.0f * c1 + c2) * 0.5f;
        float a3 = (c3 - c0 + 3.0f * (c1 - c2)) * k6;
        tab[t] = make_float4(a0, a1, a2, a3);
    }
    __syncthreads();

    const int n4     = n >> 2;
    const int stride = gridDim.x * blockDim.x;
    const int gid    = blockIdx.x * blockDim.x + threadIdx.x;

    for (int idx = gid; idx < n4; idx += stride) {
        float4 xv = reinterpret_cast<const float4*>(x)[idx];
        float4 ov;
        #pragma unroll
        for (int e = 0; e < 4; ++e) {
            float xx = (&xv.x)[e];
            float xs = xx * 69.0f;
            int   i  = (int)xs;                 // trunc; negatives clamp below
            i = i < 3 ? 3 : (i > 65 ? 65 : i);
            float s  = xs - (float)i;
            float4 a = tab[i];
            (&ov.x)[e] = fmaf(fmaf(fmaf(a.w, s, a.z), s, a.y), s, a.x);
        }
        reinterpret_cast<float4*>(out)[idx] = ov;
    }

    // generic scalar tail (n % 4 != 0) — no-op for this problem's n
    for (int k = (n4 << 2) + gid; k < n; k += stride) {
        float xs = x[k] * 69.0f;
        int   i  = (int)xs;
        i = i < 3 ? 3 : (i > 65 ? 65 : i);
        float s  = xs - (float)i;
        float4 a = tab[i];
        out[k] = fmaf(fmaf(fmaf(a.w, s, a.z), s, a.y), s, a.x);
    }
}

extern "C" void kernel_launch(void* const* d_in, const int* in_sizes, int n_in,
                              void* d_out, int out_size, void* d_ws, size_t ws_size,
                              hipStream_t stream) {
    const float* x    = (const float*)d_in[0];
    const float* coef = (const float*)d_in[1];
    float* out        = (float*)d_out;
    int n = in_sizes[0];

    // 8192 blocks = 32/CU; 67.1M elems -> 8 float4 per thread, table-build
    // prologue amortized over 32 elements/thread.
    int threads = 256;
    int blocks  = 8192;
    int max_blocks = ((n >> 2) + threads - 1) / threads;
    if (max_blocks < 1) max_blocks = 1;
    if (blocks > max_blocks) blocks = max_blocks;

    spline_kernel<<<blocks, threads, 0, stream>>>(x, coef, out, n);
}